// Round 14
// baseline (103.250 us; speedup 1.0000x reference)
//
#include <hip/hip_runtime.h>
#include <hip/hip_cooperative_groups.h>
#include <hip/hip_bf16.h>
#include <math.h>

namespace cg = cooperative_groups;

// Engram scan. Fast path: prove on-device that every step is a "create"
// (feedback == 0) and write zeros; exact sequential fallback otherwise.
//
// Soundness: n0==0 & B<=P => bank holds verbatim copies of earlier padrao
// rows and n<P always => every step creates unless a cos>=0.7 match exists
// among pairs (t, j<t). We flag at cos_q>=0.5 computed in fp8-e4m3 (RNE
// rel-err <=2^-4 => |cos_q-cos| <= ~0.135 with fp32 norms; 0.7-0.135 >
// 0.5 => conservative superset). Rows with any |x|>224 (e4m3 saturation)
// force the fallback. Also flagged: n0!=0, B>P. Threshold in squared form
// (acc>0 && acc^2 >= 0.25*pn2_t*pn2_j). MFMA C-layout = m89 mapping;
// layout errors fail-safe (false flag -> exact fallback).
//
// r14 (budget: trimain ~11us, "rest" ~15us robust across 3 prep rewrites
// => per-node dispatch overhead + serialization, cf. r4->r5->r6 gains):
// ONE cooperative kernel: phase0 chunk-prep (write-only guard[] + partial
// norms pn2p[4][B], no atomics/memset) -> grid.sync -> phase1 tri-check
// (block-stride tiles, write-only hitarr[]) -> grid.sync -> phase2 block 0
// reduces flags and runs the exact fallback inline iff flagged.

#define LIMIAR_SIM 0.7f
#define LIMIAR_NOVO 0.3f
#define LR 0.01f
#define EPSV 1e-8f
#define CHECK_T2 0.25f      // (0.5)^2 conservative vs 0.7 decision threshold
#define ABS_GUARD 224.0f    // |x| above this -> fp8 bound unsafe -> fallback

typedef __attribute__((ext_vector_type(4))) float f32x4;
typedef __attribute__((ext_vector_type(2))) long long i64x2;

// ---------------- fused fast-path kernel (D==1024, B%64==0) ----------------
__global__ __launch_bounds__(256) void k_fused(
    const float* __restrict__ padrao, const float* __restrict__ erro,
    const float* __restrict__ protos0, const float* __restrict__ forca0,
    const int* __restrict__ n0p, const float* __restrict__ gainp,
    float* __restrict__ out, int B, int P,
    unsigned int* __restrict__ guard, unsigned int* __restrict__ hitarr,
    float* __restrict__ pn2p, unsigned int* __restrict__ xq,
    float* __restrict__ wprotos, float* __restrict__ wforca,
    float* __restrict__ wprotn,
    int runnable, int force_flag, int nchunks, int ntiles) {
    cg::grid_group grid = cg::this_grid();
    __shared__ unsigned int lpk[1024];   // 4KB pack staging
    __shared__ unsigned int wred[4];
    __shared__ float rv[256];
    __shared__ int ri[256];
    const int t = threadIdx.x;
    const int lane = t & 63, wid = t >> 6;
    const int G = gridDim.x;
    f32x4* out4 = (f32x4*)out;

    // ---- phase 0: prep chunks (chunk = (16-row panel, 256-float k-chunk)) ----
    for (int c = blockIdx.x; c < nchunks; c += G) {
        __syncthreads();                 // protect lpk reuse across iterations
        int p = c >> 2, cb = c & 3;
        int r0 = p << 4;
        {   // nt zero-fill this chunk's d_out slice (16KB)
            f32x4 z = {0.f, 0.f, 0.f, 0.f};
            long long zb = (long long)c * 1024;
#pragma unroll
            for (int i = 0; i < 4; ++i)
                __builtin_nontemporal_store(z, &out4[zb + i * 256 + t]);
        }
        int k = (cb << 8) + (lane << 2);
        int cc = k >> 3, ssv = cc >> 3, jj = cc & 7;
        int slot = (ssv << 3) + ((jj & 3) << 1) + (jj >> 2);
        int su_rel = (slot >> 1) - (cb << 4);
        int lidx = (su_rel << 6) + ((slot & 1) << 1) + (lane & 1);
        bool g = false;
        for (int pass = 0; pass < 4; ++pass) {
            int i = (pass << 2) + wid;   // row 0..15 within panel
            float4 v = *(const float4*)(padrao + ((long long)(r0 + i) << 10) + k);
            float ss = v.x * v.x + v.y * v.y + v.z * v.z + v.w * v.w;
            float am = fmaxf(fmaxf(fabsf(v.x), fabsf(v.y)),
                             fmaxf(fabsf(v.z), fabsf(v.w)));
            for (int off = 32; off > 0; off >>= 1) ss += __shfl_down(ss, off);
            if (lane == 0) pn2p[cb * B + r0 + i] = ss;   // partial, no atomic
            if (__any(am > ABS_GUARD)) g = true;
            int pk = 0;
            pk = __builtin_amdgcn_cvt_pk_fp8_f32(v.x, v.y, pk, false);
            pk = __builtin_amdgcn_cvt_pk_fp8_f32(v.z, v.w, pk, true);
            lpk[lidx + i * 4] = (unsigned int)pk;
        }
        if (lane == 0) wred[wid] = g ? 1u : 0u;
        __syncthreads();
        {   // coalesced contiguous dump (256 uint4)
            const uint4* lp4 = (const uint4*)lpk;
            uint4* gq4 = (uint4*)xq + ((long long)p * 1024 + (cb << 8));
            gq4[t] = lp4[t];
        }
        if (t == 0) guard[c] = wred[0] | wred[1] | wred[2] | wred[3];
    }
    grid.sync();

    // ---- phase 1: fp8 MFMA tri-check (r11 structure, block-stride tiles) ----
    unsigned int hit = 0;
    {
        const int l15 = lane & 15, lhi = lane >> 4;
        const int kchu = 64;             // 1024/16 : 16B units per row-panel
        const i64x2* gx = (const i64x2*)xq;
        for (int tile = blockIdx.x; tile < ntiles; tile += G) {
            int ti = (int)((sqrtf(8.0f * (float)tile + 1.0f) - 1.0f) * 0.5f);
            while ((ti + 1) * (ti + 2) / 2 <= tile) ++ti;
            while (ti * (ti + 1) / 2 > tile) --ti;
            int tj = tile - ti * (ti + 1) / 2;
            int r0 = ti * 64, c0 = tj * 64;
            long long rpan = (long long)((r0 >> 4) + wid) * kchu;
            long long cp0 = (long long)(c0 >> 4) * kchu;
            f32x4 acc[4] = {};
            for (int s = 0; s < 16; ++s) {
                int uc = (s << 2) + lhi;
                i64x2 a = gx[(rpan + uc) * 16 + l15];
                i64x2 b[4];
#pragma unroll
                for (int j = 0; j < 4; ++j)
                    b[j] = gx[(cp0 + (long long)j * kchu + uc) * 16 + l15];
#pragma unroll
                for (int j = 0; j < 4; ++j) {
                    acc[j] = __builtin_amdgcn_mfma_f32_16x16x32_fp8_fp8(a[0], b[j][0], acc[j], 0, 0, 0);
                    acc[j] = __builtin_amdgcn_mfma_f32_16x16x32_fp8_fp8(a[1], b[j][1], acc[j], 0, 0, 0);
                }
            }
            int trow = r0 + wid * 16 + lhi * 4;
            float pnr[4];
#pragma unroll
            for (int r = 0; r < 4; ++r) {
                int tt = trow + r;
                pnr[r] = (tt < B) ? fmaxf(pn2p[tt] + pn2p[B + tt] + pn2p[2 * B + tt] + pn2p[3 * B + tt], 1e-16f) : 1.0f;
            }
#pragma unroll
            for (int j = 0; j < 4; ++j) {
                int cj = c0 + j * 16 + l15;
                float pc = (cj < B) ? fmaxf(pn2p[cj] + pn2p[B + cj] + pn2p[2 * B + cj] + pn2p[3 * B + cj], 1e-16f) : 1.0f;
#pragma unroll
                for (int r = 0; r < 4; ++r) {
                    int tt = trow + r;
                    float a = acc[j][r];
                    if (tt < B && cj < B && tt > cj && a > 0.0f &&
                        a * a >= CHECK_T2 * pnr[r] * pc)
                        hit = 1;
                }
            }
        }
    }
    __syncthreads();
    bool hb = __any(hit != 0);
    if (lane == 0) wred[wid] = hb ? 1u : 0u;
    __syncthreads();
    if (t == 0) hitarr[blockIdx.x] = wred[0] | wred[1] | wred[2] | wred[3];
    grid.sync();

    // ---- phase 2: block 0 reduces flags; exact fallback iff flagged ----
    if (blockIdx.x != 0) return;
    unsigned int f = 0;
    for (int i = t; i < nchunks; i += 256) f |= guard[i];
    for (int i = t; i < G; i += 256) f |= hitarr[i];
    bool fb = __any(f != 0);
    __syncthreads();
    if (lane == 0) wred[wid] = fb ? 1u : 0u;
    __syncthreads();
    if (t == 0) {
        unsigned int ff = wred[0] | wred[1] | wred[2] | wred[3];
        if (force_flag || (*n0p != 0)) ff = 1u;
        wred[0] = ff;
    }
    __syncthreads();
    if (wred[0] == 0u || !runnable) return;

    // ----- inline exact sequential fallback (256 threads, D=1024) -----
    const int NT = 256;
    const int D = 1024;
    for (long long i = t; i < (long long)P * D; i += NT) wprotos[i] = protos0[i];
    for (int i = t; i < P; i += NT) wforca[i] = forca0[i];
    __syncthreads();
    for (int j = t; j < P; j += NT) {
        const float* r = wprotos + (long long)j * D;
        float s = 0.0f;
        for (int k = 0; k < D; ++k) s += r[k] * r[k];
        wprotn[j] = fmaxf(sqrtf(s), EPSV);
    }
    int n = *n0p;
    float gain = *gainp;
    __syncthreads();
    for (int tt = 0; tt < B; ++tt) {
        const float* p = padrao + (long long)tt * D;
        float pn = fmaxf(sqrtf(fmaxf(pn2p[tt] + pn2p[B + tt] + pn2p[2 * B + tt] + pn2p[3 * B + tt], 0.0f)), EPSV);
        float best = -INFINITY; int bidx = 0;
        for (int j = t; j < n; j += NT) {
            const float* r = wprotos + (long long)j * D;
            float d = 0.0f;
            for (int k = 0; k < D; ++k) d += r[k] * p[k];
            float sim = d / (wprotn[j] * pn);
            if (sim > best) { best = sim; bidx = j; }
        }
        rv[t] = best; ri[t] = bidx;
        __syncthreads();
        for (int off = NT >> 1; off > 0; off >>= 1) {
            if (t < off) {
                float ov = rv[t + off]; int oi = ri[t + off];
                if (ov > rv[t] || (ov == rv[t] && oi < ri[t])) { rv[t] = ov; ri[t] = oi; }
            }
            __syncthreads();
        }
        float max_sim = rv[0]; int idx = ri[0];
        __syncthreads();
        float err = erro[tt];
        bool is_empty = (n == 0);
        bool do_reinf = (!is_empty) && (max_sim >= LIMIAR_SIM);
        bool do_create = is_empty || ((!do_reinf) && ((err > LIMIAR_NOVO) || (n < P)));
        if (do_create) {
            int cidx = n;
            if (n >= P) {
                float bv = INFINITY; int bi = 0;
                for (int j = t; j < P; j += NT) {
                    float fo = wforca[j];
                    if (fo < bv) { bv = fo; bi = j; }
                }
                rv[t] = bv; ri[t] = bi;
                __syncthreads();
                for (int off = NT >> 1; off > 0; off >>= 1) {
                    if (t < off) {
                        float ov = rv[t + off]; int oi = ri[t + off];
                        if (ov < rv[t] || (ov == rv[t] && oi < ri[t])) { rv[t] = ov; ri[t] = oi; }
                    }
                    __syncthreads();
                }
                cidx = ri[0];
                __syncthreads();
            }
            float* dst = wprotos + (long long)cidx * D;
            float* o = out + (long long)tt * D;
            for (int k = t; k < D; k += NT) { dst[k] = p[k]; o[k] = 0.0f; }
            if (t == 0) { wforca[cidx] = 1.0f; wprotn[cidx] = pn; }
            if (n < P) n = n + 1;
        } else if (do_reinf) {
            float* dst = wprotos + (long long)idx * D;
            float fr_new = wforca[idx] + LR;
            float* o = out + (long long)tt * D;
            float s2 = 0.0f;
            for (int k = t; k < D; k += NT) {
                float np_ = (1.0f - LR) * dst[k] + LR * p[k];
                dst[k] = np_;
                o[k] = (np_ - p[k]) * fr_new * gain;
                s2 += np_ * np_;
            }
            rv[t] = s2;
            __syncthreads();
            for (int off = NT >> 1; off > 0; off >>= 1) {
                if (t < off) rv[t] += rv[t + off];
                __syncthreads();
            }
            if (t == 0) { wforca[idx] = fr_new; wprotn[idx] = fmaxf(sqrtf(rv[0]), EPSV); }
        } else {
            const float* src = wprotos + (long long)idx * D;
            float fr = wforca[idx];
            float* o = out + (long long)tt * D;
            for (int k = t; k < D; k += NT) o[k] = (src[k] - p[k]) * fr * gain;
        }
        __syncthreads();
    }
}

// ---- ragged-path kernels (any shape; correct but not perf-critical) ----
__global__ __launch_bounds__(256) void k_norms_row(const float* __restrict__ padrao,
                                                   int B, int D, float* __restrict__ pn2,
                                                   unsigned int* __restrict__ flag,
                                                   const int* __restrict__ n0p,
                                                   int force_flag) {
    __shared__ float red[4];
    int row = blockIdx.x;
    const float* r = padrao + (long long)row * D;
    float s = 0.0f;
    for (int k = threadIdx.x; k < D; k += 256) { float v = r[k]; s += v * v; }
    for (int off = 32; off > 0; off >>= 1) s += __shfl_down(s, off);
    int wid = threadIdx.x >> 6, lane = threadIdx.x & 63;
    if (lane == 0) red[wid] = s;
    __syncthreads();
    if (threadIdx.x == 0) {
        pn2[row] = fmaxf(red[0] + red[1] + red[2] + red[3], 1e-16f);
        if (row == 0 && (force_flag || (*n0p != 0))) atomicOr(flag, 1u);
    }
}

__global__ __launch_bounds__(256) void k_tricheck(const float* __restrict__ padrao,
                                                  const float* __restrict__ pn2,
                                                  int B, int D,
                                                  unsigned int* __restrict__ flag) {
    __shared__ float As[64][65];
    __shared__ float Bs[64][65];
    int bid = blockIdx.x;
    int ti = (int)((sqrtf(8.0f * (float)bid + 1.0f) - 1.0f) * 0.5f);
    while ((ti + 1) * (ti + 2) / 2 <= bid) ++ti;
    while (ti * (ti + 1) / 2 > bid) --ti;
    int tj = bid - ti * (ti + 1) / 2;
    int r0 = ti * 64, c0 = tj * 64;
    int tid = threadIdx.x;
    int ty = tid >> 4, tx = tid & 15;
    float acc[4][4] = {};
    for (int k0 = 0; k0 < D; k0 += 64) {
        for (int s = tid; s < 64 * 64; s += 256) {
            int rr = s >> 6, cc = s & 63;
            int gc = k0 + cc;
            int gr = r0 + rr;
            As[rr][cc] = (gr < B && gc < D) ? padrao[(long long)gr * D + gc] : 0.0f;
            gr = c0 + rr;
            Bs[rr][cc] = (gr < B && gc < D) ? padrao[(long long)gr * D + gc] : 0.0f;
        }
        __syncthreads();
        for (int kk = 0; kk < 64; ++kk) {
            float a[4], b[4];
#pragma unroll
            for (int i = 0; i < 4; ++i) a[i] = As[ty * 4 + i][kk];
#pragma unroll
            for (int j = 0; j < 4; ++j) b[j] = Bs[tx * 4 + j][kk];
#pragma unroll
            for (int i = 0; i < 4; ++i)
#pragma unroll
                for (int j = 0; j < 4; ++j) acc[i][j] += a[i] * b[j];
        }
        __syncthreads();
    }
    unsigned int hit = 0;
    for (int i = 0; i < 4; ++i)
        for (int j = 0; j < 4; ++j) {
            int t = r0 + ty * 4 + i, jj = c0 + tx * 4 + j;
            if (t < B && jj < B && t > jj) {
                float a = acc[i][j];
                if (a > 0.0f && a * a >= CHECK_T2 * pn2[t] * pn2[jj]) hit = 1;
            }
        }
    if (hit) atomicOr(flag, 1u);
}

__global__ __launch_bounds__(256) void k_zero_s(float* __restrict__ out, long long n) {
    long long i = (long long)blockIdx.x * blockDim.x + threadIdx.x;
    long long stride = (long long)gridDim.x * blockDim.x;
    for (; i < n; i += stride) out[i] = 0.0f;
}

__global__ __launch_bounds__(1024) void k_fallback(
    const float* __restrict__ padrao, const float* __restrict__ erro,
    const float* __restrict__ protos0, const float* __restrict__ forca0,
    const int* __restrict__ n0p, const float* __restrict__ gainp,
    float* __restrict__ out, const float* __restrict__ pn2_arr,
    float* __restrict__ wprotos, float* __restrict__ wforca,
    float* __restrict__ wprotn, const unsigned int* __restrict__ flag,
    int runnable, int B, int D, int P) {
    if (!runnable) return;
    if (*flag == 0) return;
    const int tid = threadIdx.x;
    const int NT = blockDim.x;
    __shared__ float rv[1024];
    __shared__ int ri[1024];
    for (long long i = tid; i < (long long)P * D; i += NT) wprotos[i] = protos0[i];
    for (int i = tid; i < P; i += NT) wforca[i] = forca0[i];
    __syncthreads();
    for (int j = tid; j < P; j += NT) {
        const float* r = wprotos + (long long)j * D;
        float s = 0.0f;
        for (int k = 0; k < D; ++k) s += r[k] * r[k];
        wprotn[j] = fmaxf(sqrtf(s), EPSV);
    }
    int n = *n0p;
    float gain = *gainp;
    __syncthreads();
    for (int t = 0; t < B; ++t) {
        const float* p = padrao + (long long)t * D;
        float pn = fmaxf(sqrtf(pn2_arr[t]), EPSV);
        float best = -INFINITY; int bidx = 0;
        for (int j = tid; j < n; j += NT) {
            const float* r = wprotos + (long long)j * D;
            float d = 0.0f;
            for (int k = 0; k < D; ++k) d += r[k] * p[k];
            float sim = d / (wprotn[j] * pn);
            if (sim > best) { best = sim; bidx = j; }
        }
        rv[tid] = best; ri[tid] = bidx;
        __syncthreads();
        for (int off = NT >> 1; off > 0; off >>= 1) {
            if (tid < off) {
                float ov = rv[tid + off]; int oi = ri[tid + off];
                if (ov > rv[tid] || (ov == rv[tid] && oi < ri[tid])) { rv[tid] = ov; ri[tid] = oi; }
            }
            __syncthreads();
        }
        float max_sim = rv[0]; int idx = ri[0];
        __syncthreads();
        float err = erro[t];
        bool is_empty = (n == 0);
        bool do_reinf = (!is_empty) && (max_sim >= LIMIAR_SIM);
        bool do_create = is_empty || ((!do_reinf) && ((err > LIMIAR_NOVO) || (n < P)));
        if (do_create) {
            int cidx = n;
            if (n >= P) {
                float bv = INFINITY; int bi = 0;
                for (int j = tid; j < P; j += NT) {
                    float fo = wforca[j];
                    if (fo < bv) { bv = fo; bi = j; }
                }
                rv[tid] = bv; ri[tid] = bi;
                __syncthreads();
                for (int off = NT >> 1; off > 0; off >>= 1) {
                    if (tid < off) {
                        float ov = rv[tid + off]; int oi = ri[tid + off];
                        if (ov < rv[tid] || (ov == rv[tid] && oi < ri[tid])) { rv[tid] = ov; ri[tid] = oi; }
                    }
                    __syncthreads();
                }
                cidx = ri[0];
                __syncthreads();
            }
            float* dst = wprotos + (long long)cidx * D;
            float* o = out + (long long)t * D;
            for (int k = tid; k < D; k += NT) { dst[k] = p[k]; o[k] = 0.0f; }
            if (tid == 0) { wforca[cidx] = 1.0f; wprotn[cidx] = pn; }
            if (n < P) n = n + 1;
        } else if (do_reinf) {
            float* dst = wprotos + (long long)idx * D;
            float fr_new = wforca[idx] + LR;
            float* o = out + (long long)t * D;
            float s2 = 0.0f;
            for (int k = tid; k < D; k += NT) {
                float np_ = (1.0f - LR) * dst[k] + LR * p[k];
                dst[k] = np_;
                o[k] = (np_ - p[k]) * fr_new * gain;
                s2 += np_ * np_;
            }
            rv[tid] = s2;
            __syncthreads();
            for (int off = NT >> 1; off > 0; off >>= 1) {
                if (tid < off) rv[tid] += rv[tid + off];
                __syncthreads();
            }
            if (tid == 0) { wforca[idx] = fr_new; wprotn[idx] = fmaxf(sqrtf(rv[0]), EPSV); }
        } else {
            const float* src = wprotos + (long long)idx * D;
            float fr = wforca[idx];
            float* o = out + (long long)t * D;
            for (int k = tid; k < D; k += NT) o[k] = (src[k] - p[k]) * fr * gain;
        }
        __syncthreads();
    }
}

extern "C" void kernel_launch(void* const* d_in, const int* in_sizes, int n_in,
                              void* d_out, int out_size, void* d_ws, size_t ws_size,
                              hipStream_t stream) {
    const float* padrao  = (const float*)d_in[0];
    const float* erro    = (const float*)d_in[1];
    const float* protos0 = (const float*)d_in[2];
    const float* forca0  = (const float*)d_in[3];
    const int*   n0p     = (const int*)d_in[5];
    const float* gainp   = (const float*)d_in[6];
    const int B = in_sizes[1];
    const int D = (B > 0) ? in_sizes[0] / B : 0;
    const int P = in_sizes[3];

    char* ws = (char*)d_ws;
    // fused-path layout
    unsigned int* guard = (unsigned int*)ws;                 // 512 u32
    unsigned int* hitarr = (unsigned int*)(ws + 2048);       // 512 u32
    float* pn2p = (float*)(ws + 4096);                       // 4*B floats
    size_t off_xq = (4096 + (size_t)B * 16 + 63) & ~(size_t)63;
    unsigned int* xq = (unsigned int*)(ws + off_xq);
    size_t off_protos = (off_xq + (size_t)B * (size_t)D + 63) & ~(size_t)63;
    float* wprotos = (float*)(ws + off_protos);
    size_t off_forca = off_protos + (size_t)P * (size_t)D * 4;
    float* wforca = (float*)(ws + off_forca);
    size_t off_protn = off_forca + (size_t)P * 4;
    float* wprotn = (float*)(ws + off_protn);
    size_t need_total = off_protn + (size_t)P * 4;
    size_t need_fast = off_xq + (size_t)B * (size_t)D;

    int runnable = (ws_size >= need_total) ? 1 : 0;
    int force_flag = (B > P) ? 1 : 0;
    int use_fused = ((B % 64) == 0) && (D == 1024) && (ws_size >= need_fast)
                    && ((long long)out_size == (long long)B * D);

    int nT = (B + 63) / 64;
    int ntiles = nT * (nT + 1) / 2;
    int nchunks = B >> 2;                // (B/16) panels * 4 chunks
    long long outN = (long long)out_size;

    if (use_fused) {
        int occ = 0, numCU = 0, dev = 0;
        hipGetDevice(&dev);
        hipOccupancyMaxActiveBlocksPerMultiprocessor(&occ, k_fused, 256, 0);
        hipDeviceGetAttribute(&numCU, hipDeviceAttributeMultiprocessorCount, dev);
        int cap = occ * numCU;
        int G = nchunks < 512 ? nchunks : 512;
        if (G > cap) G = cap;
        if (G >= 8) {
            float* outf = (float*)d_out;
            void* args[] = {
                (void*)&padrao, (void*)&erro, (void*)&protos0, (void*)&forca0,
                (void*)&n0p, (void*)&gainp, (void*)&outf, (void*)&B, (void*)&P,
                (void*)&guard, (void*)&hitarr, (void*)&pn2p, (void*)&xq,
                (void*)&wprotos, (void*)&wforca, (void*)&wprotn,
                (void*)&runnable, (void*)&force_flag, (void*)&nchunks, (void*)&ntiles
            };
            hipLaunchCooperativeKernel((void*)k_fused, dim3(G), dim3(256),
                                       args, 0, stream);
            return;
        }
        // capacity too low -> fall through to ragged path
    }

    // ---- ragged path (r13 structure): flag at ws, pn2 at ws+64 ----
    unsigned int* flag = (unsigned int*)ws;
    float* pn2 = (float*)(ws + 64);
    hipMemsetAsync(ws, 0, 64 + (size_t)B * 4, stream);
    k_norms_row<<<B, 256, 0, stream>>>(padrao, B, D, pn2, flag, n0p, force_flag);
    int nblk = ntiles;
    k_tricheck<<<nblk, 256, 0, stream>>>(padrao, pn2, B, D, flag);
    int zb = (int)((outN + 255) / 256); if (zb > 2048) zb = 2048; if (zb < 1) zb = 1;
    k_zero_s<<<zb, 256, 0, stream>>>((float*)d_out, outN);
    k_fallback<<<1, 1024, 0, stream>>>(padrao, erro, protos0, forca0, n0p, gainp,
                                       (float*)d_out, pn2, wprotos, wforca, wprotn,
                                       flag, runnable, B, D, P);
}

// Round 15
// 21.772 us; speedup vs baseline: 4.7423x; 4.7423x over previous
//
#include <hip/hip_runtime.h>
#include <hip/hip_bf16.h>
#include <math.h>

// Engram scan. Fast path: prove on-device that every step is a "create"
// (feedback == 0) and write zeros; exact sequential fallback otherwise.
//
// Soundness: n0==0 & B<=P => bank holds verbatim copies of earlier padrao
// rows and n<P always => every step creates unless a cos>=0.7 match exists
// among pairs (t, j<t). We flag at cos_q>=0.5 computed in fp8-e4m3 (RNE
// rel-err <=2^-4 => |cos_q-cos| <= ~0.135 with fp32 norms; 0.7-0.135 >
// 0.5 => conservative superset). Rows with any |x|>224 (e4m3 saturation)
// set guard[row] -> fallback. Also flagged: n0!=0, B>P. MFMA C-layout =
// m89 mapping; layout errors fail-safe (false flag -> exact fallback).
//
// r15 (r14 cooperative = 103us: grid.sync machinery ~130us idle, reverted):
// EXACT r11 structure (26.3us known-good) minus the memset node:
//  * prep writes per-row guard[] with plain stores (no init/atomic needed);
//    block 0 plain-stores flag = force|n0 (sole writer in prep).
//  * trimain ORs hit into flag (stream-ordered after prep -- race-free).
//  * fallback reduces flag | OR(guard[]) before its early-exit.
// Fast path: 3 nodes (prep, trimain, fallback), was 4.

#define LIMIAR_SIM 0.7f
#define LIMIAR_NOVO 0.3f
#define LR 0.01f
#define EPSV 1e-8f
#define CHECK_THRESH 0.5f   // conservative vs 0.7 decision threshold
#define ABS_GUARD 224.0f    // |x| above this -> fp8 bound unsafe -> fallback

typedef __attribute__((ext_vector_type(4))) float f32x4;
typedef __attribute__((ext_vector_type(2))) long long i64x2;

// -- kernel 1: row norms + packed fp8 convert + nt zero-fill + guard row --
__global__ __launch_bounds__(256) void k_prep(const float* __restrict__ padrao,
                                              int B, int D, float* __restrict__ pn,
                                              unsigned int* __restrict__ xq,
                                              int do_conv,
                                              f32x4* __restrict__ out4,
                                              long long n4z, int do_zero,
                                              unsigned int* __restrict__ flag,
                                              unsigned int* __restrict__ guard,
                                              const int* __restrict__ n0p,
                                              int force_flag) {
    __shared__ float red[4];
    __shared__ float redm[4];
    int row = blockIdx.x;
    if (do_zero) {
        long long chunk = (n4z + gridDim.x - 1) / gridDim.x;
        long long zb = (long long)row * chunk;
        long long ze = zb + chunk; if (ze > n4z) ze = n4z;
        f32x4 z = {0.f, 0.f, 0.f, 0.f};
        for (long long i = zb + threadIdx.x; i < ze; i += 256)
            __builtin_nontemporal_store(z, &out4[i]);
    }
    const float* r = padrao + (long long)row * D;
    float s = 0.0f, amax = 0.0f;
    if ((D & 3) == 0) {
        for (int k = threadIdx.x * 4; k < D; k += 1024) {
            float4 v = *(const float4*)(r + k);
            s += v.x * v.x + v.y * v.y + v.z * v.z + v.w * v.w;
            amax = fmaxf(amax, fmaxf(fmaxf(fabsf(v.x), fabsf(v.y)),
                                     fmaxf(fabsf(v.z), fabsf(v.w))));
            if (do_conv) {
                // fp8 pack, 4 elems -> u32 (RNE via v_cvt_pk_fp8_f32)
                int pk = 0;
                pk = __builtin_amdgcn_cvt_pk_fp8_f32(v.x, v.y, pk, false);
                pk = __builtin_amdgcn_cvt_pk_fp8_f32(v.z, v.w, pk, true);
                // slot permutation: chunk c=k>>3 (8 fp8), s=c>>3, j=c&7
                // slot = 8s + 2*(j&3) + (j>>2); 16B unit su=slot>>1, half=slot&1
                int c = k >> 3, ss = c >> 3, j = c & 7;
                int slot = (ss << 3) + ((j & 3) << 1) + (j >> 2);
                int su = slot >> 1, h = slot & 1;
                long long u32i = (((long long)(row >> 4) * (D >> 4) + su) * 16
                                  + (row & 15)) * 4 + h * 2 + ((k >> 2) & 1);
                xq[u32i] = (unsigned int)pk;
            }
        }
    } else {
        for (int k = threadIdx.x; k < D; k += 256) { float v = r[k]; s += v * v; }
    }
    for (int off = 32; off > 0; off >>= 1) {
        s += __shfl_down(s, off);
        amax = fmaxf(amax, __shfl_down(amax, off));
    }
    int wid = threadIdx.x >> 6, lane = threadIdx.x & 63;
    if (lane == 0) { red[wid] = s; redm[wid] = amax; }
    __syncthreads();
    if (threadIdx.x == 0) {
        float tot = red[0] + red[1] + red[2] + red[3];
        pn[row] = fmaxf(sqrtf(tot), EPSV);
        float bm = fmaxf(fmaxf(redm[0], redm[1]), fmaxf(redm[2], redm[3]));
        guard[row] = (do_conv && bm > ABS_GUARD) ? 1u : 0u;   // plain store
        if (row == 0) *flag = (force_flag || (*n0p != 0)) ? 1u : 0u;
    }
}

// ------- kernel 2: fp8 MFMA tri-check, M-split, XCD-swizzled blocks -------
// 64x64 tile/block, 4 waves; wave w owns rows [r0+16w,+16) over full K.
// Superstep s (K=64): 1 A + 4 B 16B loads -> 8 fp8 MFMAs (K=32 each).
__global__ __launch_bounds__(256) void k_trimain(const unsigned int* __restrict__ xq,
                                                 const float* __restrict__ pn,
                                                 int B, int D,
                                                 unsigned int* __restrict__ flag) {
    // T1 bijective XCD swizzle (m204)
    int nblk = gridDim.x;
    int orig = blockIdx.x;
    int q8 = nblk >> 3, r8 = nblk & 7;
    int xcd = orig & 7, lin = orig >> 3;
    int bid = (xcd < r8 ? xcd * (q8 + 1) : r8 * (q8 + 1) + (xcd - r8) * q8) + lin;
    int ti = (int)((sqrtf(8.0f * (float)bid + 1.0f) - 1.0f) * 0.5f);
    while ((ti + 1) * (ti + 2) / 2 <= bid) ++ti;
    while (ti * (ti + 1) / 2 > bid) --ti;
    int tj = bid - ti * (ti + 1) / 2;
    int r0 = ti * 64, c0 = tj * 64;
    int tid = threadIdx.x;
    int w = tid >> 6, l = tid & 63;
    int l15 = l & 15, lhi = l >> 4;
    const int kchu = D >> 4;                // 16B units per row-panel
    const i64x2* gx = (const i64x2*)xq;
    long long rpan = (long long)((r0 >> 4) + w) * kchu;
    long long cpan0 = (long long)(c0 >> 4) * kchu;
    f32x4 acc[4] = {};
    int nss = D >> 6;                       // supersteps (K=64 each)
    for (int s = 0; s < nss; ++s) {
        int uc = (s << 2) + lhi;            // unit = 4s + lhi
        i64x2 a = gx[(rpan + uc) * 16 + l15];
        i64x2 b[4];
#pragma unroll
        for (int j = 0; j < 4; ++j)
            b[j] = gx[(cpan0 + (long long)j * kchu + uc) * 16 + l15];
#pragma unroll
        for (int j = 0; j < 4; ++j) {
            acc[j] = __builtin_amdgcn_mfma_f32_16x16x32_fp8_fp8(a[0], b[j][0], acc[j], 0, 0, 0);
            acc[j] = __builtin_amdgcn_mfma_f32_16x16x32_fp8_fp8(a[1], b[j][1], acc[j], 0, 0, 0);
        }
    }
    // threshold on registers; C layout (m89): col=l&15, row=lhi*4+r
    int trow = r0 + w * 16 + lhi * 4;
    float pnr[4];
#pragma unroll
    for (int r = 0; r < 4; ++r) {
        int t = trow + r;
        pnr[r] = (t < B) ? pn[t] : 1.0f;
    }
    unsigned int hit = 0;
#pragma unroll
    for (int j = 0; j < 4; ++j) {
        int jj = c0 + j * 16 + l15;
        float pc = (jj < B) ? pn[jj] : 1.0f;
#pragma unroll
        for (int r = 0; r < 4; ++r) {
            int t = trow + r;
            if (t < B && jj < B && t > jj && acc[j][r] >= CHECK_THRESH * pnr[r] * pc)
                hit = 1;
        }
    }
    if (hit) atomicOr(flag, 1u);
}

// ------------- fp32 tri-check (ragged-shape fallback path) -------------
__global__ __launch_bounds__(256) void k_tricheck(const float* __restrict__ padrao,
                                                  const float* __restrict__ pn,
                                                  int B, int D,
                                                  unsigned int* __restrict__ flag) {
    __shared__ float As[64][65];
    __shared__ float Bs[64][65];
    int bid = blockIdx.x;
    int ti = (int)((sqrtf(8.0f * (float)bid + 1.0f) - 1.0f) * 0.5f);
    while ((ti + 1) * (ti + 2) / 2 <= bid) ++ti;
    while (ti * (ti + 1) / 2 > bid) --ti;
    int tj = bid - ti * (ti + 1) / 2;
    int r0 = ti * 64, c0 = tj * 64;
    int tid = threadIdx.x;
    int ty = tid >> 4, tx = tid & 15;
    float acc[4][4] = {};
    for (int k0 = 0; k0 < D; k0 += 64) {
        for (int s = tid; s < 64 * 64; s += 256) {
            int rr = s >> 6, cc = s & 63;
            int gc = k0 + cc;
            int gr = r0 + rr;
            As[rr][cc] = (gr < B && gc < D) ? padrao[(long long)gr * D + gc] : 0.0f;
            gr = c0 + rr;
            Bs[rr][cc] = (gr < B && gc < D) ? padrao[(long long)gr * D + gc] : 0.0f;
        }
        __syncthreads();
        for (int kk = 0; kk < 64; ++kk) {
            float a[4], b[4];
#pragma unroll
            for (int i = 0; i < 4; ++i) a[i] = As[ty * 4 + i][kk];
#pragma unroll
            for (int j = 0; j < 4; ++j) b[j] = Bs[tx * 4 + j][kk];
#pragma unroll
            for (int i = 0; i < 4; ++i)
#pragma unroll
                for (int j = 0; j < 4; ++j) acc[i][j] += a[i] * b[j];
        }
        __syncthreads();
    }
    unsigned int hit = 0;
    for (int i = 0; i < 4; ++i)
        for (int j = 0; j < 4; ++j) {
            int t = r0 + ty * 4 + i, jj = c0 + tx * 4 + j;
            if (t < B && jj < B && t > jj) {
                if (acc[i][j] >= CHECK_THRESH * pn[t] * pn[jj]) hit = 1;
            }
        }
    if (hit) atomicOr(flag, 1u);
}

// ---------------- zero kernel (ragged path only) ----------------
__global__ __launch_bounds__(256) void k_zero_s(float* __restrict__ out, long long n) {
    long long i = (long long)blockIdx.x * blockDim.x + threadIdx.x;
    long long stride = (long long)gridDim.x * blockDim.x;
    for (; i < n; i += stride) out[i] = 0.0f;
}

// ------- kernel 3: exact sequential fallback (runs iff flag|guard set) -------
__global__ __launch_bounds__(1024) void k_fallback(
    const float* __restrict__ padrao, const float* __restrict__ erro,
    const float* __restrict__ protos0, const float* __restrict__ forca0,
    const int* __restrict__ n0p, const float* __restrict__ gainp,
    float* __restrict__ out, const float* __restrict__ pn_arr,
    float* __restrict__ wprotos, float* __restrict__ wforca,
    float* __restrict__ wprotn, const unsigned int* __restrict__ flag,
    const unsigned int* __restrict__ guard, int nguard,
    int runnable, int B, int D, int P) {
    if (!runnable) return;
    const int tid = threadIdx.x;
    const int NT = blockDim.x;
    __shared__ unsigned int fsh;
    if (tid == 0) fsh = *flag;
    __syncthreads();
    unsigned int lf = 0;
    for (int i = tid; i < nguard; i += NT) lf |= guard[i];
    if (lf) atomicOr(&fsh, 1u);
    __syncthreads();
    if (fsh == 0u) return;
    __shared__ float rv[1024];
    __shared__ int ri[1024];
    for (long long i = tid; i < (long long)P * D; i += NT) wprotos[i] = protos0[i];
    for (int i = tid; i < P; i += NT) wforca[i] = forca0[i];
    __syncthreads();
    for (int j = tid; j < P; j += NT) {
        const float* r = wprotos + (long long)j * D;
        float s = 0.0f;
        for (int k = 0; k < D; ++k) s += r[k] * r[k];
        wprotn[j] = fmaxf(sqrtf(s), EPSV);
    }
    int n = *n0p;
    float gain = *gainp;
    __syncthreads();
    for (int t = 0; t < B; ++t) {
        const float* p = padrao + (long long)t * D;
        float pn = pn_arr[t];
        float best = -INFINITY; int bidx = 0;
        for (int j = tid; j < n; j += NT) {
            const float* r = wprotos + (long long)j * D;
            float d = 0.0f;
            for (int k = 0; k < D; ++k) d += r[k] * p[k];
            float sim = d / (wprotn[j] * pn);
            if (sim > best) { best = sim; bidx = j; }
        }
        rv[tid] = best; ri[tid] = bidx;
        __syncthreads();
        for (int off = NT >> 1; off > 0; off >>= 1) {
            if (tid < off) {
                float ov = rv[tid + off]; int oi = ri[tid + off];
                if (ov > rv[tid] || (ov == rv[tid] && oi < ri[tid])) { rv[tid] = ov; ri[tid] = oi; }
            }
            __syncthreads();
        }
        float max_sim = rv[0]; int idx = ri[0];
        __syncthreads();
        float err = erro[t];
        bool is_empty = (n == 0);
        bool do_reinf = (!is_empty) && (max_sim >= LIMIAR_SIM);
        bool do_create = is_empty || ((!do_reinf) && ((err > LIMIAR_NOVO) || (n < P)));
        if (do_create) {
            int cidx = n;
            if (n >= P) {
                float bv = INFINITY; int bi = 0;
                for (int j = tid; j < P; j += NT) {
                    float f = wforca[j];
                    if (f < bv) { bv = f; bi = j; }
                }
                rv[tid] = bv; ri[tid] = bi;
                __syncthreads();
                for (int off = NT >> 1; off > 0; off >>= 1) {
                    if (tid < off) {
                        float ov = rv[tid + off]; int oi = ri[tid + off];
                        if (ov < rv[tid] || (ov == rv[tid] && oi < ri[tid])) { rv[tid] = ov; ri[tid] = oi; }
                    }
                    __syncthreads();
                }
                cidx = ri[0];
                __syncthreads();
            }
            float* dst = wprotos + (long long)cidx * D;
            float* o = out + (long long)t * D;
            for (int k = tid; k < D; k += NT) { dst[k] = p[k]; o[k] = 0.0f; }
            if (tid == 0) { wforca[cidx] = 1.0f; wprotn[cidx] = pn; }
            if (n < P) n = n + 1;
        } else if (do_reinf) {
            float* dst = wprotos + (long long)idx * D;
            float fr_new = wforca[idx] + LR;
            float* o = out + (long long)t * D;
            float s2 = 0.0f;
            for (int k = tid; k < D; k += NT) {
                float np_ = (1.0f - LR) * dst[k] + LR * p[k];
                dst[k] = np_;
                o[k] = (np_ - p[k]) * fr_new * gain;
                s2 += np_ * np_;
            }
            rv[tid] = s2;
            __syncthreads();
            for (int off = NT >> 1; off > 0; off >>= 1) {
                if (tid < off) rv[tid] += rv[tid + off];
                __syncthreads();
            }
            if (tid == 0) { wforca[idx] = fr_new; wprotn[idx] = fmaxf(sqrtf(rv[0]), EPSV); }
        } else {
            const float* src = wprotos + (long long)idx * D;
            float fr = wforca[idx];
            float* o = out + (long long)t * D;
            for (int k = tid; k < D; k += NT) o[k] = (src[k] - p[k]) * fr * gain;
        }
        __syncthreads();
    }
}

extern "C" void kernel_launch(void* const* d_in, const int* in_sizes, int n_in,
                              void* d_out, int out_size, void* d_ws, size_t ws_size,
                              hipStream_t stream) {
    const float* padrao  = (const float*)d_in[0];
    const float* erro    = (const float*)d_in[1];
    const float* protos0 = (const float*)d_in[2];
    const float* forca0  = (const float*)d_in[3];
    const int*   n0p     = (const int*)d_in[5];
    const float* gainp   = (const float*)d_in[6];
    const int B = in_sizes[1];
    const int D = (B > 0) ? in_sizes[0] / B : 0;
    const int P = in_sizes[3];

    char* ws = (char*)d_ws;
    unsigned int* flag = (unsigned int*)ws;
    float* pn = (float*)(ws + 64);
    size_t off_guard = 64 + (size_t)B * 4;
    unsigned int* guard = (unsigned int*)(ws + off_guard);
    size_t off_xq = (off_guard + (size_t)B * 4 + 63) & ~(size_t)63;
    unsigned int* xq = (unsigned int*)(ws + off_xq);
    size_t off_protos = (off_xq + (size_t)B * (size_t)D + 63) & ~(size_t)63;  // fp8: B*D bytes
    float* wprotos = (float*)(ws + off_protos);
    size_t off_forca = off_protos + (size_t)P * (size_t)D * 4;
    float* wforca = (float*)(ws + off_forca);
    size_t off_protn = off_forca + (size_t)P * 4;
    float* wprotn = (float*)(ws + off_protn);
    size_t need_total = off_protn + (size_t)P * 4;
    size_t need_fast = off_xq + (size_t)B * (size_t)D;

    int runnable = (ws_size >= need_total) ? 1 : 0;
    int force_flag = (B > P) ? 1 : 0;
    int use_mfma = ((B % 64) == 0) && ((D % 128) == 0) && (ws_size >= need_fast)
                   && ((long long)out_size == (long long)B * D);

    int nT = (B + 63) / 64;
    int nblk = nT * (nT + 1) / 2;
    long long outN = (long long)out_size;

    if (use_mfma) {
        long long n4 = outN >> 2;   // outN = B*D, D%128==0 => divisible by 4
        k_prep<<<B, 256, 0, stream>>>(padrao, B, D, pn, xq, 1,
                                      (f32x4*)d_out, n4, 1, flag, guard, n0p, force_flag);
        k_trimain<<<nblk, 256, 0, stream>>>(xq, pn, B, D, flag);
        k_fallback<<<1, 1024, 0, stream>>>(padrao, erro, protos0, forca0, n0p, gainp,
                                           (float*)d_out, pn, wprotos, wforca, wprotn,
                                           flag, guard, B, runnable, B, D, P);
    } else {
        hipMemsetAsync(ws, 0, 64 + (size_t)B * 4, stream);
        k_prep<<<B, 256, 0, stream>>>(padrao, B, D, pn, xq, 0,
                                      (f32x4*)d_out, 0, 0, flag, guard, n0p, force_flag);
        k_tricheck<<<nblk, 256, 0, stream>>>(padrao, pn, B, D, flag);
        int zb = (int)((outN + 255) / 256); if (zb > 2048) zb = 2048; if (zb < 1) zb = 1;
        k_zero_s<<<zb, 256, 0, stream>>>((float*)d_out, outN);
        k_fallback<<<1, 1024, 0, stream>>>(padrao, erro, protos0, forca0, n0p, gainp,
                                           (float*)d_out, pn, wprotos, wforca, wprotn,
                                           flag, guard, 0, runnable, B, D, P);
    }
}